// Round 2
// baseline (182.727 us; speedup 1.0000x reference)
//
#include <hip/hip_runtime.h>
#include <stdint.h>

// Problem dims (fixed by the reference)
#define NB   8192
#define NZ   10
#define CIN  512
#define COUT 512
#define MM   3
#define ALPHA 0.04419417382415922f   // 1/sqrt(512)

#define BM 32
#define BN 64
#define BK 32
#define KITERS (CIN / BK)
#define MAX_MTILES 266   // sum_z ceil(n_z/32) <= 8192/32 + 10

typedef short bf16x8 __attribute__((ext_vector_type(8)));   // 8 bf16 in 4 VGPRs
typedef float f32x4  __attribute__((ext_vector_type(4)));

__device__ __forceinline__ uint16_t f2bf(float f) {
    union { float f; uint32_t i; } v; v.f = f;
    uint32_t x = v.i;
    x += 0x7fffu + ((x >> 16) & 1u);   // RNE
    return (uint16_t)(x >> 16);
}
__device__ __forceinline__ uint32_t pack2(float a, float b) {
    return (uint32_t)f2bf(a) | ((uint32_t)f2bf(b) << 16);
}

// ---------------- K0: species decode (one-hot argmax) ----------------
__global__ __launch_bounds__(256)
void decode_kernel(const float* __restrict__ attrs, int* __restrict__ species) {
    int b = blockIdx.x * 256 + threadIdx.x;
    if (b >= NB) return;
    const float* a = attrs + (size_t)b * NZ;
    int s = 0;
    #pragma unroll
    for (int z = 0; z < NZ; z++) if (a[z] > 0.5f) s = z;
    species[b] = s;
}

// ---------------- K1: single-block counting sort ----------------
__global__ __launch_bounds__(256)
void sort_kernel(const int* __restrict__ species, int* __restrict__ sorted,
                 int* __restrict__ offsets, int* __restrict__ tile_offsets) {
    __shared__ int cnt[NZ];
    __shared__ int cur[NZ];
    const int tid = threadIdx.x;
    if (tid < NZ) cnt[tid] = 0;
    __syncthreads();
    for (int i = tid; i < NB; i += 256) atomicAdd(&cnt[species[i]], 1);
    __syncthreads();
    if (tid == 0) {
        int off = 0, toff = 0;
        for (int z = 0; z < NZ; z++) {
            offsets[z] = off;
            tile_offsets[z] = toff;
            cur[z] = off;
            off  += cnt[z];
            toff += (cnt[z] + BM - 1) / BM;
        }
        offsets[NZ] = off;
        tile_offsets[NZ] = toff;
    }
    __syncthreads();
    for (int i = tid; i < NB; i += 256) {
        int s = species[i];
        int pos = atomicAdd(&cur[s], 1);
        sorted[pos] = i;
    }
}

// ---------------- K2: per-species MFMA GEMM ----------------
// out[node, C, d] = alpha * sum_c W[z][C][c] * t[node][c][d]
// A = t-slice  [m=node][k=c]  (three planes, one per d)
// B = W        [n=C]  [k=c]
// D[m][n] per mfma_f32_16x16x32_bf16: C/D col=lane&15, row=(lane>>4)*4+reg.
__global__ __launch_bounds__(256)
void gemm_kernel(const float* __restrict__ t, const float* __restrict__ w,
                 const int* __restrict__ sorted, const int* __restrict__ offsets,
                 const int* __restrict__ tile_offsets, float* __restrict__ out) {
    __shared__ ushort As[MM][BM][BK + 8];   // pad +16B: conflict-free b128 reads
    __shared__ ushort Bs[BN][BK + 8];
    __shared__ int snode[BM];

    const int tz = blockIdx.x;
    if (tz >= tile_offsets[NZ]) return;      // uniform early-exit, before barriers
    int z = 0;
    #pragma unroll
    for (int i = 1; i < NZ; i++) if (tile_offsets[i] <= tz) z = i;

    const int seg_start = offsets[z];
    const int seg_end   = offsets[z + 1];
    const int m_base    = seg_start + (tz - tile_offsets[z]) * BM;
    const int tid = threadIdx.x;

    if (tid < BM) {
        int pos = m_base + tid;
        snode[tid] = sorted[min(pos, seg_end - 1)];   // clamp: edge rows recompute row, store skipped
    }
    __syncthreads();

    const int Cbase = blockIdx.y * BN;

    // staging roles
    const int aNode = tid >> 3, aPart = tid & 7;   // 8 threads/node, 12 floats each
    const int bRow  = tid >> 2, bPart = tid & 3;   // 4 threads/row,  8 floats each
    const float* tnode = t + (size_t)snode[aNode] * (CIN * MM) + aPart * 12;
    const float* wrow  = w + ((size_t)z * COUT + Cbase + bRow) * CIN + bPart * 8;

    // compute roles
    const int wv = tid >> 6, lane = tid & 63;
    const int wm = wv & 1, wn = wv >> 1;
    const int q = lane >> 4, mr = lane & 15;

    f32x4 acc[MM][2];
    #pragma unroll
    for (int d = 0; d < MM; d++)
        #pragma unroll
        for (int s2 = 0; s2 < 2; s2++)
            acc[d][s2] = (f32x4){0.f, 0.f, 0.f, 0.f};

    for (int kt = 0; kt < KITERS; kt++) {
        const int c0 = kt * BK;
        // ---- A staging: t[node, c0..c0+31, 0..2] = 96 contiguous floats/node
        const float4* asrc = (const float4*)(tnode + c0 * MM);
        float4 f0 = asrc[0], f1 = asrc[1], f2 = asrc[2];
        float v[12] = {f0.x, f0.y, f0.z, f0.w, f1.x, f1.y, f1.z, f1.w,
                       f2.x, f2.y, f2.z, f2.w};
        // v[j]: c_local = aPart*4 + j/3, d = j%3 -> per d, 4 consecutive k
        #pragma unroll
        for (int d = 0; d < MM; d++) {
            uint2 wq;
            wq.x = pack2(v[d],     v[d + 3]);
            wq.y = pack2(v[d + 6], v[d + 9]);
            *(uint2*)&As[d][aNode][aPart * 4] = wq;
        }
        // ---- B staging: W[z, Cbase+bRow, c0 + bPart*8 .. +7]
        const float4* bsrc = (const float4*)(wrow + c0);
        float4 g0 = bsrc[0], g1 = bsrc[1];
        uint4 bw;
        bw.x = pack2(g0.x, g0.y); bw.y = pack2(g0.z, g0.w);
        bw.z = pack2(g1.x, g1.y); bw.w = pack2(g1.z, g1.w);
        *(uint4*)&Bs[bRow][bPart * 8] = bw;
        __syncthreads();

        // ---- fragments + MFMA
        bf16x8 af[MM], bfr[2];
        #pragma unroll
        for (int d = 0; d < MM; d++)
            af[d] = *(const bf16x8*)&As[d][wm * 16 + mr][q * 8];
        #pragma unroll
        for (int s2 = 0; s2 < 2; s2++)
            bfr[s2] = *(const bf16x8*)&Bs[wn * 32 + s2 * 16 + mr][q * 8];
        #pragma unroll
        for (int d = 0; d < MM; d++)
            #pragma unroll
            for (int s2 = 0; s2 < 2; s2++)
                acc[d][s2] = __builtin_amdgcn_mfma_f32_16x16x32_bf16(
                    af[d], bfr[s2], acc[d][s2], 0, 0, 0);
        __syncthreads();
    }

    // ---- epilogue: out[node, C, 0..2] contiguous fp32
    #pragma unroll
    for (int s2 = 0; s2 < 2; s2++) {
        const int Cg = Cbase + wn * 32 + s2 * 16 + mr;
        #pragma unroll
        for (int r = 0; r < 4; r++) {
            const int m_local = wm * 16 + q * 4 + r;
            if (m_base + m_local < seg_end) {
                float* o = out + (size_t)snode[m_local] * (COUT * MM) + Cg * MM;
                o[0] = ALPHA * acc[0][s2][r];
                o[1] = ALPHA * acc[1][s2][r];
                o[2] = ALPHA * acc[2][s2][r];
            }
        }
    }
}

extern "C" void kernel_launch(void* const* d_in, const int* in_sizes, int n_in,
                              void* d_out, int out_size, void* d_ws, size_t ws_size,
                              hipStream_t stream) {
    const float* t     = (const float*)d_in[0];   // [B, IN, 3]  fp32
    const float* attrs = (const float*)d_in[1];   // [B, Z]      fp32 one-hot
    const float* w     = (const float*)d_in[2];   // [Z, OUT, IN] fp32
    float* out = (float*)d_out;                   // [B, OUT, 3] fp32

    int* species      = (int*)d_ws;               // [8192]
    int* sorted       = species + NB;             // [8192]
    int* offsets      = sorted + NB;              // [11]
    int* tile_offsets = offsets + 16;             // [11]

    hipLaunchKernelGGL(decode_kernel, dim3(NB / 256), dim3(256), 0, stream,
                       attrs, species);
    hipLaunchKernelGGL(sort_kernel, dim3(1), dim3(256), 0, stream,
                       species, sorted, offsets, tile_offsets);
    hipLaunchKernelGGL(gemm_kernel, dim3(MAX_MTILES, COUT / BN), dim3(256), 0, stream,
                       t, w, sorted, offsets, tile_offsets, out);
}